// Round 1
// baseline (672.235 us; speedup 1.0000x reference)
//
#include <hip/hip_runtime.h>

// Sizes (fixed by the problem)
#define HOUT 15
#define WOUT 15
// input  (32, 32, 32, 32, 16)  fp32
// ncv    (32, 32, 15, 15, 16)  fp32
// w      (3, 3, 32, 4, 4, 32)  fp32
// out    (32, 32, 15, 15, 16)  fp32

// One 32-lane group per output position (b,h,w); lane = m.
// 8 groups per 256-thread block -> 7200/8 = 900 blocks.
__global__ __launch_bounds__(256) void caps_fused(
    const float* __restrict__ input,
    const float* __restrict__ ncv,
    const float* __restrict__ wt,
    const float* __restrict__ gamma,
    const float* __restrict__ beta,
    float* __restrict__ out)
{
    const int tid  = threadIdx.x;
    const int grp  = tid >> 5;          // 0..7 : position within block
    const int lane = tid & 31;          // m index

    const int pos = blockIdx.x * 8 + grp;   // 0..7199
    const int b   = pos / (HOUT * WOUT);
    const int hw  = pos % (HOUT * WOUT);
    const int h   = hw / WOUT;
    const int wo  = hw % WOUT;

    // ncv[b, m=lane, h, wo, 0..15]  (a outer, d inner: j = a*4+d)
    const float* ncv_p = ncv + ((((size_t)b * 32 + lane) * HOUT + h) * WOUT + wo) * 16;
    float cv[16];
#pragma unroll
    for (int j = 0; j < 16; j += 4) {
        float4 t = *(const float4*)(ncv_p + j);
        cv[j] = t.x; cv[j+1] = t.y; cv[j+2] = t.z; cv[j+3] = t.w;
    }

    float acc[16];
#pragma unroll
    for (int j = 0; j < 16; ++j) acc[j] = 0.0f;

    const int h0 = h * 2, w0 = wo * 2;

    for (int n = 0; n < 32; ++n) {
        const float* ipn = input + ((((size_t)b * 32 + n) * 32 + h0) * 32 + w0) * 16;
        const float* wpn = wt + (size_t)n * 512 + lane;   // w[k,l,n,x,d,m]: +(k*3+l)*16384 +(x*4+d)*32
#pragma unroll
        for (int k = 0; k < 3; ++k) {
#pragma unroll
            for (int l = 0; l < 3; ++l) {
                // inp[b, n, 2h+k, 2w+l, 0..15]  (a outer, x inner: a*4+x)
                const float* ip = ipn + (k * 32 + l) * 16;
                float av[16];
#pragma unroll
                for (int j = 0; j < 16; j += 4) {
                    float4 t = *(const float4*)(ip + j);
                    av[j] = t.x; av[j+1] = t.y; av[j+2] = t.z; av[j+3] = t.w;
                }

                const float* wp = wpn + (k * 3 + l) * 16384;

                // u[a,d] = sum_x av[a,x] * w[x,d,m]
                float u[16];
#pragma unroll
                for (int j = 0; j < 16; ++j) u[j] = 0.0f;
#pragma unroll
                for (int x = 0; x < 4; ++x) {
#pragma unroll
                    for (int d = 0; d < 4; ++d) {
                        float wxd = wp[(x * 4 + d) * 32];   // lane-coalesced
#pragma unroll
                        for (int a = 0; a < 4; ++a)
                            u[a * 4 + d] = fmaf(av[a * 4 + x], wxd, u[a * 4 + d]);
                    }
                }

                // logit = scale * <u, ncv>
                float logit = 0.0f;
#pragma unroll
                for (int j = 0; j < 16; ++j) logit = fmaf(u[j], cv[j], logit);
                logit *= 0.25f;   // 1/sqrt(16)

                // softmax over m (the 32 lanes of this group)
                float mx = logit;
#pragma unroll
                for (int off = 16; off > 0; off >>= 1)
                    mx = fmaxf(mx, __shfl_xor(mx, off, 32));
                float e = __expf(logit - mx);
                float s = e;
#pragma unroll
                for (int off = 16; off > 0; off >>= 1)
                    s += __shfl_xor(s, off, 32);
                // reference's second normalization (/(sum+1e-10)) is a ~1e-10
                // relative perturbation -- far below the 7.2e-2 threshold.
                float p = e * __builtin_amdgcn_rcpf(s);

#pragma unroll
                for (int j = 0; j < 16; ++j) acc[j] = fmaf(p, u[j], acc[j]);
            }
        }
    }

    // LayerNorm over the 16 register-resident elements (per lane = per m)
    float mu = 0.0f;
#pragma unroll
    for (int j = 0; j < 16; ++j) mu += acc[j];
    mu *= 0.0625f;
    float var = 0.0f;
#pragma unroll
    for (int j = 0; j < 16; ++j) { float d = acc[j] - mu; var = fmaf(d, d, var); }
    var *= 0.0625f;
    float rstd = __builtin_amdgcn_rsqf(var + 1e-5f);

    float* op = out + ((((size_t)b * 32 + lane) * HOUT + h) * WOUT + wo) * 16;
#pragma unroll
    for (int j = 0; j < 16; j += 4) {
        float4 g  = *(const float4*)(gamma + j);
        float4 be = *(const float4*)(beta + j);
        float4 r;
        r.x = (acc[j+0] - mu) * rstd * g.x + be.x;
        r.y = (acc[j+1] - mu) * rstd * g.y + be.y;
        r.z = (acc[j+2] - mu) * rstd * g.z + be.z;
        r.w = (acc[j+3] - mu) * rstd * g.w + be.w;
        *(float4*)(op + j) = r;
    }
}

extern "C" void kernel_launch(void* const* d_in, const int* in_sizes, int n_in,
                              void* d_out, int out_size, void* d_ws, size_t ws_size,
                              hipStream_t stream) {
    const float* input = (const float*)d_in[0];
    const float* ncv   = (const float*)d_in[1];
    const float* wt    = (const float*)d_in[2];
    const float* gamma = (const float*)d_in[3];
    const float* beta  = (const float*)d_in[4];
    float* out = (float*)d_out;

    caps_fused<<<dim3(900), dim3(256), 0, stream>>>(input, ncv, wt, gamma, beta, out);
}